// Round 8
// baseline (2825.344 us; speedup 1.0000x reference)
//
#include <hip/hip_runtime.h>
#include <stddef.h>

// ---------- types / helpers ----------
using short8 = __attribute__((ext_vector_type(8))) short;
using f32x4  = __attribute__((ext_vector_type(4))) float;
using f32x16 = __attribute__((ext_vector_type(16))) float;
using u16x4  = __attribute__((ext_vector_type(4))) unsigned short;

struct U128 { unsigned long long a, b; };

__device__ __forceinline__ unsigned short cvt_bf16(float f) {
    unsigned u = __builtin_bit_cast(unsigned, f);
    u += 0x7fffu + ((u >> 16) & 1u);          // RNE
    return (unsigned short)(u >> 16);
}

__device__ __forceinline__ void gload_lds16(const void* g, void* l) {
    __builtin_amdgcn_global_load_lds(
        (const __attribute__((address_space(1))) unsigned*)g,
        (__attribute__((address_space(3))) unsigned*)l, 16, 0, 0);
}

#define MFMA16(a, b, c) __builtin_amdgcn_mfma_f32_16x16x32_bf16((a), (b), (c), 0, 0, 0)
#define MFMA32(a, b, c) __builtin_amdgcn_mfma_f32_32x32x16_bf16((a), (b), (c), 0, 0, 0)

// B=128, T=256, I=H=K=1024
// ---------- weight conversion: f32 -> bf16 ----------
__global__ __launch_bounds__(256) void convert_w(const float* __restrict__ Wi,
                                                 const float* __restrict__ Wh,
                                                 unsigned short* __restrict__ Wib,
                                                 unsigned short* __restrict__ Whb) {
    const float* src = blockIdx.y ? Wh : Wi;
    unsigned short* dst = blockIdx.y ? Whb : Wib;
    int base = blockIdx.x * 2048 + threadIdx.x * 8;
#pragma unroll
    for (int c = 0; c < 2; ++c) {
        float4 v = *(const float4*)(src + base + c * 4);
        u16x4 o;
        o.x = cvt_bf16(v.x); o.y = cvt_bf16(v.y); o.z = cvt_bf16(v.z); o.w = cvt_bf16(v.w);
        *(u16x4*)(dst + base + c * 4) = o;
    }
}

// ---------- h init + flag zero ----------
__global__ __launch_bounds__(256) void init_h(const float* __restrict__ hidden,
                                              unsigned short* __restrict__ h0,
                                              unsigned* __restrict__ flags) {
    int row = blockIdx.x;
    int tid = threadIdx.x;
    float4 v = *(const float4*)(hidden + (size_t)row * 1024 + tid * 4);
    u16x4 o;
    o.x = cvt_bf16(v.x); o.y = cvt_bf16(v.y); o.z = cvt_bf16(v.z); o.w = cvt_bf16(v.w);
    *(u16x4*)(h0 + (size_t)row * 1024 + tid * 4) = o;
    if (blockIdx.x == 0) {
        for (int i = tid; i < 512; i += 256) flags[i] = 0;
    }
}

// ---------- pre-GEMM: pre[t][b][n] = sum_k x[b][t][k] * Wi[n][k] + bi[n] ----------
__global__ __launch_bounds__(256) void pre_gemm(const float* __restrict__ x,
                                                const unsigned short* __restrict__ Wib,
                                                const float* __restrict__ bi,
                                                float* __restrict__ pre) {
    __shared__ unsigned short Alds[128 * 64];
    __shared__ unsigned short Blds[128 * 64];
    const int tid  = threadIdx.x;
    const int lane = tid & 63, wid = tid >> 6;
    const int wr = wid >> 1, wc = wid & 1;     // 2x2 waves, 64x64 each
    const int t  = blockIdx.y;                 // time index == M-tile
    const int n0 = blockIdx.x * 128;

    f32x4 acc[4][4] = {};

    for (int kt = 0; kt < 16; ++kt) {
        const int k0 = kt * 64;
        __syncthreads();
#pragma unroll
        for (int c = 0; c < 8; ++c) {
            int flat = c * 256 + tid;          // 0..2047
            int row = flat >> 4;               // 0..127  (batch b)
            int seg = flat & 15;               // 16 segs of 4 f32
            float4 v = *(const float4*)(x + (size_t)row * 262144 + (size_t)t * 1024 + k0 + seg * 4);
            u16x4 h;
            h.x = cvt_bf16(v.x); h.y = cvt_bf16(v.y); h.z = cvt_bf16(v.z); h.w = cvt_bf16(v.w);
            *(u16x4*)&Alds[row * 64 + seg * 4] = h;
        }
#pragma unroll
        for (int c = 0; c < 4; ++c) {
            int flat = c * 256 + tid;          // 0..1023
            int row = flat >> 3;               // 0..127
            int seg = flat & 7;                // 8 segs of 8 bf16
            gload_lds16(Wib + (size_t)(n0 + row) * 1024 + k0 + seg * 8, &Blds[flat * 8]);
        }
        __syncthreads();
#pragma unroll
        for (int ks = 0; ks < 2; ++ks) {
            short8 a[4], b[4];
#pragma unroll
            for (int i = 0; i < 4; ++i)
                a[i] = *(const short8*)&Alds[(wr * 64 + i * 16 + (lane & 15)) * 64 + ks * 32 + (lane >> 4) * 8];
#pragma unroll
            for (int j = 0; j < 4; ++j)
                b[j] = *(const short8*)&Blds[(wc * 64 + j * 16 + (lane & 15)) * 64 + ks * 32 + (lane >> 4) * 8];
#pragma unroll
            for (int i = 0; i < 4; ++i)
#pragma unroll
                for (int j = 0; j < 4; ++j)
                    acc[i][j] = MFMA16(a[i], b[j], acc[i][j]);
        }
    }
    const int rbase = wr * 64 + (lane >> 4) * 4;
    const int cbase = n0 + wc * 64 + (lane & 15);
#pragma unroll
    for (int i = 0; i < 4; ++i) {
#pragma unroll
        for (int j = 0; j < 4; ++j) {
            int n = cbase + j * 16;
            float bv = bi[n];
#pragma unroll
            for (int r = 0; r < 4; ++r) {
                int m = rbase + i * 16 + r;    // batch b
                pre[((size_t)t * 128 + m) * 1024 + n] = acc[i][j][r] + bv;
            }
        }
    }
}

// ---------- persistent scan kernel ----------
// 256 blocks x 256 threads. group g = bid&7 (g<4: fwd rows g*32.., g>=4: bwd),
// ni = bid>>3 -> cols ni*32. Per step: all waves poll flags; each wave gathers
// its A-fragments (h rows, its K=256 slice) DIRECTLY into MFMA lane layout
// (no LDS A-path); 16x MFMA32 K-split; Red-LDS partial exchange; ONE sync;
// wave 0 alone reduces + softplus + h-store + ack + flag + out while waves
// 1-3 move on to the next poll.
__global__ __launch_bounds__(256, 1) void rnn_scan(const unsigned short* __restrict__ Whb,
                                                   const float* __restrict__ pre,
                                                   const float* __restrict__ bh,
                                                   unsigned short* __restrict__ ha,
                                                   unsigned short* __restrict__ hb,
                                                   float* __restrict__ out,
                                                   unsigned* __restrict__ flags) {
    __shared__ float Red[4][1024];               // 16KB cross-wave reduce

    const int tid  = threadIdx.x;
    const int lane = tid & 63, wid = tid >> 6;
    const int bid  = blockIdx.x;
    const int g    = bid & 7, ni = bid >> 3;
    const int m0   = g * 32, n0 = ni * 32;
    const bool fwd = (g < 4);
    unsigned* gflags = flags + g * 32;

    // Wh b-frags resident: wave wid owns k in [wid*256, wid*256+256)
    short8 bfrag[16];
    {
        const unsigned short* bp = Whb + (size_t)(n0 + (lane & 31)) * 1024
                                 + wid * 256 + (lane >> 5) * 8;
#pragma unroll
        for (int ks = 0; ks < 16; ++ks)
            bfrag[ks] = *(const short8*)(bp + ks * 16);
    }

    // A-gather lane offset: row = lane&31, k-slice base = wid*256 + (lane>>5)*8
    const size_t arow_off = (size_t)(lane & 31) * 2048 + wid * 512 + (lane >> 5) * 16;

    // wave0 epilogue constants: lane covers row em = lane>>1, cols en..en+15
    const int em  = lane >> 1;
    const int en  = (lane & 1) * 16;
    const int emg = m0 + em;
    const int eb  = emg & 127;
    f32x4 bh4[4];
#pragma unroll
    for (int q = 0; q < 4; ++q)
        bh4[q] = *(const f32x4*)(bh + n0 + en + q * 4);
    const float* prebase = pre + (size_t)eb * 1024 + n0 + en;
    float* outbase       = out + (size_t)eb * 524288 + (fwd ? 0 : 1024) + n0 + en;

    for (int s = 0; s < 256; ++s) {
        const unsigned short* hin = (s & 1) ? hb : ha;
        unsigned short* hout      = (s & 1) ? ha : hb;
        const int prow = fwd ? s : 255 - s;

        // wave0: prefetch pre tile (independent of h)
        f32x4 pv[4];
        if (wid == 0) {
#pragma unroll
            for (int q = 0; q < 4; ++q)
                pv[q] = *(const f32x4*)(prebase + (size_t)prow * 131072 + q * 4);
        }

        // all-wave poll of the 32 producer flags (no sync needed after)
        if (s > 0) {
            int fuel = 1 << 22;
            unsigned v;
            do {
                v = __hip_atomic_load(&gflags[lane & 31], __ATOMIC_RELAXED,
                                      __HIP_MEMORY_SCOPE_AGENT);
            } while (!__all((int)(v >= (unsigned)s)) && --fuel);
        }

        // gather A directly into MFMA lane layout: 32 x 8B relaxed loads
        const char* hsrc = (const char*)(hin + (size_t)m0 * 1024) + arow_off;
        unsigned long long alo[16], ahi[16];
#pragma unroll
        for (int i = 0; i < 16; ++i) {
            alo[i] = __hip_atomic_load((const unsigned long long*)(hsrc + i * 32),
                                       __ATOMIC_RELAXED, __HIP_MEMORY_SCOPE_AGENT);
            ahi[i] = __hip_atomic_load((const unsigned long long*)(hsrc + i * 32 + 8),
                                       __ATOMIC_RELAXED, __HIP_MEMORY_SCOPE_AGENT);
        }

        // K-split MFMA: each wave 32x32 partial over its K=256 slice
        f32x16 acc0 = {}, acc1 = {};
#pragma unroll
        for (int ks = 0; ks < 16; ++ks) {
            U128 t2{alo[ks], ahi[ks]};
            short8 a = __builtin_bit_cast(short8, t2);
            if (ks & 1) acc1 = MFMA32(a, bfrag[ks], acc1);
            else        acc0 = MFMA32(a, bfrag[ks], acc0);
        }
        f32x16 acc = acc0 + acc1;
#pragma unroll
        for (int r = 0; r < 16; ++r) {
            int row = (r & 3) + 8 * (r >> 2) + 4 * (lane >> 5);
            Red[wid][row * 32 + (lane & 31)] = acc[r];
        }
        __syncthreads();

        // wave0 finisher: reduce + softplus + h-store + ack + flag + out
        if (wid == 0) {
            f32x4 ov[4];
#pragma unroll
            for (int q = 0; q < 4; ++q) {
                const int o = (em * 32 + en) + q * 4;
                f32x4 v0 = *(const f32x4*)&Red[0][o];
                f32x4 v1 = *(const f32x4*)&Red[1][o];
                f32x4 v2 = *(const f32x4*)&Red[2][o];
                f32x4 v3 = *(const f32x4*)&Red[3][o];
                f32x4 vv = v0 + v1 + v2 + v3 + pv[q] + bh4[q];
                u16x4 hh;
#pragma unroll
                for (int j = 0; j < 4; ++j) {
                    float xv = vv[j];
                    float hv = (5.0f * xv > 20.0f) ? xv : 0.2f * log1pf(__expf(5.0f * xv));
                    ov[q][j] = hv;
                    hh[j] = cvt_bf16(hv);
                }
                __hip_atomic_store(
                    (unsigned long long*)(hout + (size_t)emg * 1024 + n0 + en + q * 4),
                    __builtin_bit_cast(unsigned long long, hh),
                    __ATOMIC_RELAXED, __HIP_MEMORY_SCOPE_AGENT);
            }
            asm volatile("s_waitcnt vmcnt(0)" ::: "memory");   // h stores acked
            if (lane == 0 && s < 255)
                __hip_atomic_store(&gflags[ni], (unsigned)(s + 1),
                                   __ATOMIC_RELAXED, __HIP_MEMORY_SCOPE_AGENT);
            const int tout = fwd ? ((239 - s) & 255) : s;
#pragma unroll
            for (int q = 0; q < 4; ++q)
                __builtin_nontemporal_store(ov[q],
                    (f32x4*)(outbase + (size_t)tout * 2048 + q * 4));
        }
    }
}

// ---------- launch ----------
extern "C" void kernel_launch(void* const* d_in, const int* in_sizes, int n_in,
                              void* d_out, int out_size, void* d_ws, size_t ws_size,
                              hipStream_t stream) {
    const float* x      = (const float*)d_in[0];
    const float* hidden = (const float*)d_in[1];
    const float* Wi     = (const float*)d_in[2];
    const float* bi     = (const float*)d_in[3];
    const float* Wh     = (const float*)d_in[4];
    const float* bh     = (const float*)d_in[5];
    float* out = (float*)d_out;

    char* ws = (char*)d_ws;
    float*          pre = (float*)ws;                               // 128 MB
    unsigned short* Wib = (unsigned short*)(ws + 134217728);        // 2 MB
    unsigned short* Whb = (unsigned short*)(ws + 136314880);        // 2 MB
    unsigned short* ha  = (unsigned short*)(ws + 138412032);        // 512 KB
    unsigned short* hb  = (unsigned short*)(ws + 138936320);        // 512 KB
    unsigned*     flags = (unsigned*)(ws + 139460608);              // 2 KB

    convert_w<<<dim3(512, 2), 256, 0, stream>>>(Wi, Wh, Wib, Whb);
    init_h<<<256, 256, 0, stream>>>(hidden, ha, flags);
    pre_gemm<<<dim3(8, 256), 256, 0, stream>>>(x, Wib, bi, pre);
    rnn_scan<<<256, 256, 0, stream>>>(Whb, pre, bh, ha, hb, out, flags);
}

// Round 9
// 2028.934 us; speedup vs baseline: 1.3925x; 1.3925x over previous
//
#include <hip/hip_runtime.h>
#include <stddef.h>

// ---------- types / helpers ----------
using short8 = __attribute__((ext_vector_type(8))) short;
using f32x4  = __attribute__((ext_vector_type(4))) float;
using f32x16 = __attribute__((ext_vector_type(16))) float;
using u16x4  = __attribute__((ext_vector_type(4))) unsigned short;
using u64    = unsigned long long;

__device__ __forceinline__ unsigned short cvt_bf16(float f) {
    unsigned u = __builtin_bit_cast(unsigned, f);
    u += 0x7fffu + ((u >> 16) & 1u);          // RNE
    return (unsigned short)(u >> 16);
}

__device__ __forceinline__ void gload_lds16(const void* g, void* l) {
    __builtin_amdgcn_global_load_lds(
        (const __attribute__((address_space(1))) unsigned*)g,
        (__attribute__((address_space(3))) unsigned*)l, 16, 0, 0);
}

#define MFMA16(a, b, c) __builtin_amdgcn_mfma_f32_16x16x32_bf16((a), (b), (c), 0, 0, 0)
#define MFMA32(a, b, c) __builtin_amdgcn_mfma_f32_32x32x16_bf16((a), (b), (c), 0, 0, 0)

// B=128, T=256, I=H=K=1024
// ---------- weight conversion: f32 -> bf16 ----------
__global__ __launch_bounds__(256) void convert_w(const float* __restrict__ Wi,
                                                 const float* __restrict__ Wh,
                                                 unsigned short* __restrict__ Wib,
                                                 unsigned short* __restrict__ Whb) {
    const float* src = blockIdx.y ? Wh : Wi;
    unsigned short* dst = blockIdx.y ? Whb : Wib;
    int base = blockIdx.x * 2048 + threadIdx.x * 8;
#pragma unroll
    for (int c = 0; c < 2; ++c) {
        float4 v = *(const float4*)(src + base + c * 4);
        u16x4 o;
        o.x = cvt_bf16(v.x); o.y = cvt_bf16(v.y); o.z = cvt_bf16(v.z); o.w = cvt_bf16(v.w);
        *(u16x4*)(dst + base + c * 4) = o;
    }
}

// ---------- h init + flag zero ----------
__global__ __launch_bounds__(256) void init_h(const float* __restrict__ hidden,
                                              unsigned short* __restrict__ h0,
                                              unsigned* __restrict__ flags) {
    int row = blockIdx.x;
    int tid = threadIdx.x;
    float4 v = *(const float4*)(hidden + (size_t)row * 1024 + tid * 4);
    u16x4 o;
    o.x = cvt_bf16(v.x); o.y = cvt_bf16(v.y); o.z = cvt_bf16(v.z); o.w = cvt_bf16(v.w);
    *(u16x4*)(h0 + (size_t)row * 1024 + tid * 4) = o;
    if (blockIdx.x == 0) {
        for (int i = tid; i < 512; i += 256) flags[i] = 0;
    }
}

// ---------- pre-GEMM: pre[t][b][n] = sum_k x[b][t][k] * Wi[n][k] + bi[n] ----------
__global__ __launch_bounds__(256) void pre_gemm(const float* __restrict__ x,
                                                const unsigned short* __restrict__ Wib,
                                                const float* __restrict__ bi,
                                                float* __restrict__ pre) {
    __shared__ unsigned short Alds[128 * 64];
    __shared__ unsigned short Blds[128 * 64];
    const int tid  = threadIdx.x;
    const int lane = tid & 63, wid = tid >> 6;
    const int wr = wid >> 1, wc = wid & 1;     // 2x2 waves, 64x64 each
    const int t  = blockIdx.y;                 // time index == M-tile
    const int n0 = blockIdx.x * 128;

    f32x4 acc[4][4] = {};

    for (int kt = 0; kt < 16; ++kt) {
        const int k0 = kt * 64;
        __syncthreads();
#pragma unroll
        for (int c = 0; c < 8; ++c) {
            int flat = c * 256 + tid;          // 0..2047
            int row = flat >> 4;               // 0..127  (batch b)
            int seg = flat & 15;               // 16 segs of 4 f32
            float4 v = *(const float4*)(x + (size_t)row * 262144 + (size_t)t * 1024 + k0 + seg * 4);
            u16x4 h;
            h.x = cvt_bf16(v.x); h.y = cvt_bf16(v.y); h.z = cvt_bf16(v.z); h.w = cvt_bf16(v.w);
            *(u16x4*)&Alds[row * 64 + seg * 4] = h;
        }
#pragma unroll
        for (int c = 0; c < 4; ++c) {
            int flat = c * 256 + tid;          // 0..1023
            int row = flat >> 3;               // 0..127
            int seg = flat & 7;                // 8 segs of 8 bf16
            gload_lds16(Wib + (size_t)(n0 + row) * 1024 + k0 + seg * 8, &Blds[flat * 8]);
        }
        __syncthreads();
#pragma unroll
        for (int ks = 0; ks < 2; ++ks) {
            short8 a[4], b[4];
#pragma unroll
            for (int i = 0; i < 4; ++i)
                a[i] = *(const short8*)&Alds[(wr * 64 + i * 16 + (lane & 15)) * 64 + ks * 32 + (lane >> 4) * 8];
#pragma unroll
            for (int j = 0; j < 4; ++j)
                b[j] = *(const short8*)&Blds[(wc * 64 + j * 16 + (lane & 15)) * 64 + ks * 32 + (lane >> 4) * 8];
#pragma unroll
            for (int i = 0; i < 4; ++i)
#pragma unroll
                for (int j = 0; j < 4; ++j)
                    acc[i][j] = MFMA16(a[i], b[j], acc[i][j]);
        }
    }
    const int rbase = wr * 64 + (lane >> 4) * 4;
    const int cbase = n0 + wc * 64 + (lane & 15);
#pragma unroll
    for (int i = 0; i < 4; ++i) {
#pragma unroll
        for (int j = 0; j < 4; ++j) {
            int n = cbase + j * 16;
            float bv = bi[n];
#pragma unroll
            for (int r = 0; r < 4; ++r) {
                int m = rbase + i * 16 + r;    // batch b
                pre[((size_t)t * 128 + m) * 1024 + n] = acc[i][j][r] + bv;
            }
        }
    }
}

// ---------- persistent dual-chain scan kernel ----------
// 128 blocks x 256 threads. g = bid&3 (4 groups), ni = bid>>2 (32 col-blocks).
// Each block advances BOTH chains: fwd rows g*32.., bwd rows 128+g*32..,
// cols ni*32... Shared Wh bfrag. One combined poll + one gather latency per
// TWO steps; B-chain loads land under F-chain compute.
__global__ __launch_bounds__(256, 1) void rnn_scan(const unsigned short* __restrict__ Whb,
                                                   const float* __restrict__ pre,
                                                   const float* __restrict__ bh,
                                                   unsigned short* __restrict__ ha,
                                                   unsigned short* __restrict__ hb,
                                                   float* __restrict__ out,
                                                   unsigned* __restrict__ flags) {
    __shared__ unsigned short AldsF[32 * 1024];  // 64KB fwd h-slice (swizzled)
    __shared__ unsigned short AldsB[32 * 1024];  // 64KB bwd h-slice (swizzled)
    __shared__ float Red[4][1024];               // 16KB cross-wave reduce

    const int tid  = threadIdx.x;
    const int lane = tid & 63, wid = tid >> 6;
    const int bid  = blockIdx.x;
    const int g    = bid & 3, ni = bid >> 2;
    const int m0f  = g * 32;                     // fwd rows
    const int m0b  = 128 + g * 32;               // bwd rows
    const int n0   = ni * 32;
    unsigned* gflags = flags + g * 64;           // [0..31] fwd, [32..63] bwd

    // Wh b-frags resident (shared by both chains): wave wid owns K [wid*256 ..)
    short8 bfrag[16];
    {
        const unsigned short* bp = Whb + (size_t)(n0 + (lane & 31)) * 1024
                                 + wid * 256 + (lane >> 5) * 8;
#pragma unroll
        for (int ks = 0; ks < 16; ++ks)
            bfrag[ks] = *(const short8*)(bp + ks * 16);
    }

    // epilogue constants: thread owns 4 consecutive n at one row
    const int mloc = tid >> 3;            // 0..31
    const int nloc = (tid & 7) * 4;       // 0..28
    const int bb   = m0f + mloc;          // batch row (same for both chains)
    const int n    = n0 + nloc;
    const float4 bh4 = *(const float4*)(bh + n);
    const float* prebase = pre + (size_t)bb * 1024 + n;
    float* outF = out + (size_t)bb * 524288 + n;
    float* outB = out + (size_t)bb * 524288 + 1024 + n;

    const int   kb0   = wid * 512 + (lane >> 5) * 16;
    const int   aswz  = (lane & 7) << 4;
    const char* arowF = (const char*)AldsF + (lane & 31) * 2048;
    const char* arowB = (const char*)AldsB + (lane & 31) * 2048;
    const int   colswz = tid * 8;

    for (int s = 0; s < 256; ++s) {
        const unsigned short* hin = (s & 1) ? hb : ha;
        unsigned short* hout      = (s & 1) ? ha : hb;

        // pre tiles for both chains (independent of h)
        float4 pvF = *(const float4*)(prebase + (size_t)s * 131072);
        float4 pvB = *(const float4*)(prebase + (size_t)(255 - s) * 131072);

        // combined poll: lanes 0..31 watch fwd producers, 32..63 bwd producers
        if (s > 0) {
            int fuel = 1 << 22;
            unsigned v;
            do {
                v = __hip_atomic_load(&gflags[lane], __ATOMIC_RELAXED,
                                      __HIP_MEMORY_SCOPE_AGENT);
            } while (!__all((int)(v >= (unsigned)s)) && --fuel);
        }

        // gather both chains' h rows (8B per thread per row)
        const u64* hsF = (const u64*)(hin + (size_t)m0f * 1024);
        const u64* hsB = (const u64*)(hin + (size_t)m0b * 1024);
        u64 tF[32], tB[32];
#pragma unroll
        for (int i = 0; i < 32; ++i)
            tF[i] = __hip_atomic_load(&hsF[(size_t)i * 256 + tid],
                                      __ATOMIC_RELAXED, __HIP_MEMORY_SCOPE_AGENT);
#pragma unroll
        for (int i = 0; i < 32; ++i)
            tB[i] = __hip_atomic_load(&hsB[(size_t)i * 256 + tid],
                                      __ATOMIC_RELAXED, __HIP_MEMORY_SCOPE_AGENT);

        // ---- chain F ----
#pragma unroll
        for (int i = 0; i < 32; ++i)
            *(u64*)((char*)AldsF + i * 2048 + (colswz ^ ((i & 7) << 4))) = tF[i];
        __syncthreads();                                   // S1

        {
            f32x16 acc0 = {}, acc1 = {};
#pragma unroll
            for (int ks = 0; ks < 16; ++ks) {
                short8 a = *(const short8*)(arowF + ((kb0 + ks * 32) ^ aswz));
                if (ks & 1) acc1 = MFMA32(a, bfrag[ks], acc1);
                else        acc0 = MFMA32(a, bfrag[ks], acc0);
            }
            f32x16 acc = acc0 + acc1;
#pragma unroll
            for (int r = 0; r < 16; ++r) {
                int row = (r & 3) + 8 * (r >> 2) + 4 * (lane >> 5);
                Red[wid][row * 32 + (lane & 31)] = acc[r];
            }
        }
        __syncthreads();                                   // S2

        f32x4 ovF;
        {
            const int o = tid * 4;
            f32x4 q0 = *(const f32x4*)&Red[0][o];
            f32x4 q1 = *(const f32x4*)&Red[1][o];
            f32x4 q2 = *(const f32x4*)&Red[2][o];
            f32x4 q3 = *(const f32x4*)&Red[3][o];
            f32x4 vv = q0 + q1 + q2 + q3;
            u16x4 hh;
#pragma unroll
            for (int j = 0; j < 4; ++j) {
                float xv = vv[j] + ((const float*)&pvF)[j] + ((const float*)&bh4)[j];
                float hv = (5.0f * xv > 20.0f) ? xv : 0.2f * log1pf(__expf(5.0f * xv));
                ovF[j] = hv;
                hh[j] = cvt_bf16(hv);
            }
            __hip_atomic_store((u64*)(hout + (size_t)(m0f + mloc) * 1024 + n),
                               __builtin_bit_cast(u64, hh),
                               __ATOMIC_RELAXED, __HIP_MEMORY_SCOPE_AGENT);
        }
        asm volatile("s_waitcnt vmcnt(0)" ::: "memory");   // F h-stores acked
        __syncthreads();                                   // S3
        if (tid == 0 && s < 255)
            __hip_atomic_store(&gflags[ni], (unsigned)(s + 1),
                               __ATOMIC_RELAXED, __HIP_MEMORY_SCOPE_AGENT);
        {
            const int toutF = (239 - s) & 255;
            __builtin_nontemporal_store(ovF, (f32x4*)(outF + (size_t)toutF * 2048));
        }

        // ---- chain B ----
#pragma unroll
        for (int i = 0; i < 32; ++i)
            *(u64*)((char*)AldsB + i * 2048 + (colswz ^ ((i & 7) << 4))) = tB[i];
        __syncthreads();                                   // S4

        {
            f32x16 acc0 = {}, acc1 = {};
#pragma unroll
            for (int ks = 0; ks < 16; ++ks) {
                short8 a = *(const short8*)(arowB + ((kb0 + ks * 32) ^ aswz));
                if (ks & 1) acc1 = MFMA32(a, bfrag[ks], acc1);
                else        acc0 = MFMA32(a, bfrag[ks], acc0);
            }
            f32x16 acc = acc0 + acc1;
#pragma unroll
            for (int r = 0; r < 16; ++r) {
                int row = (r & 3) + 8 * (r >> 2) + 4 * (lane >> 5);
                Red[wid][row * 32 + (lane & 31)] = acc[r];
            }
        }
        __syncthreads();                                   // S5

        f32x4 ovB;
        {
            const int o = tid * 4;
            f32x4 q0 = *(const f32x4*)&Red[0][o];
            f32x4 q1 = *(const f32x4*)&Red[1][o];
            f32x4 q2 = *(const f32x4*)&Red[2][o];
            f32x4 q3 = *(const f32x4*)&Red[3][o];
            f32x4 vv = q0 + q1 + q2 + q3;
            u16x4 hh;
#pragma unroll
            for (int j = 0; j < 4; ++j) {
                float xv = vv[j] + ((const float*)&pvB)[j] + ((const float*)&bh4)[j];
                float hv = (5.0f * xv > 20.0f) ? xv : 0.2f * log1pf(__expf(5.0f * xv));
                ovB[j] = hv;
                hh[j] = cvt_bf16(hv);
            }
            __hip_atomic_store((u64*)(hout + (size_t)(m0b + mloc) * 1024 + n),
                               __builtin_bit_cast(u64, hh),
                               __ATOMIC_RELAXED, __HIP_MEMORY_SCOPE_AGENT);
        }
        asm volatile("s_waitcnt vmcnt(0)" ::: "memory");   // B h-stores acked
        __syncthreads();                                   // S6
        if (tid == 0 && s < 255)
            __hip_atomic_store(&gflags[32 + ni], (unsigned)(s + 1),
                               __ATOMIC_RELAXED, __HIP_MEMORY_SCOPE_AGENT);
        {
            const int toutB = s;
            __builtin_nontemporal_store(ovB, (f32x4*)(outB + (size_t)toutB * 2048));
        }
    }
}

// ---------- launch ----------
extern "C" void kernel_launch(void* const* d_in, const int* in_sizes, int n_in,
                              void* d_out, int out_size, void* d_ws, size_t ws_size,
                              hipStream_t stream) {
    const float* x      = (const float*)d_in[0];
    const float* hidden = (const float*)d_in[1];
    const float* Wi     = (const float*)d_in[2];
    const float* bi     = (const float*)d_in[3];
    const float* Wh     = (const float*)d_in[4];
    const float* bh     = (const float*)d_in[5];
    float* out = (float*)d_out;

    char* ws = (char*)d_ws;
    float*          pre = (float*)ws;                               // 128 MB
    unsigned short* Wib = (unsigned short*)(ws + 134217728);        // 2 MB
    unsigned short* Whb = (unsigned short*)(ws + 136314880);        // 2 MB
    unsigned short* ha  = (unsigned short*)(ws + 138412032);        // 512 KB
    unsigned short* hb  = (unsigned short*)(ws + 138936320);        // 512 KB
    unsigned*     flags = (unsigned*)(ws + 139460608);              // 2 KB

    convert_w<<<dim3(512, 2), 256, 0, stream>>>(Wi, Wh, Wib, Whb);
    init_h<<<256, 256, 0, stream>>>(hidden, ha, flags);
    pre_gemm<<<dim3(8, 256), 256, 0, stream>>>(x, Wib, bi, pre);
    rnn_scan<<<128, 256, 0, stream>>>(Whb, pre, bh, ha, hb, out, flags);
}